// Round 1
// baseline (46.499 us; speedup 1.0000x reference)
//
#include <hip/hip_runtime.h>

// LIF integrate-fire-reset over the time axis.
// x: [B=64, C=2048, T=256] f32 row-major  -> rows = B*C = 131072, each row 256 contiguous floats.
// Recurrence per row: u_t = TAU*u_{t-1}*(1-s_{t-1}) + x_t ; s_t = (u_t > VTH).
//
// Strategy: one thread per row. The row is contiguous, so direct per-thread reads
// are stride-1024B (uncoalesced). We stage chunks of 32 timesteps for 256 rows
// through LDS with a 36-word row stride (conflict-free for both b128 writes and
// b128 reads), compute 32 steps in registers, and exchange spikes as 32-bit masks
// (1 LDS word per row) before coalesced float4 stores.

#define T_LEN 256
#define CT 32              // timesteps per chunk
#define NCH (T_LEN / CT)   // 8 chunks
#define RPB 256            // rows per block == threads per block
#define XS_STRIDE 36       // LDS words per row (32 + 4 pad: keeps 16B align, even bank spread)

#define TAU 0.25f
#define VTH 0.5f

__global__ __launch_bounds__(RPB, 4)
void lif_kernel(const float* __restrict__ x, float* __restrict__ out) {
    __shared__ __align__(16) float xs[RPB * XS_STRIDE];  // 36864 B
    __shared__ unsigned int smask[RPB];                  // 1024 B

    const int tid = threadIdx.x;
    const long rbase = (long)blockIdx.x * RPB;

    const float4* __restrict__ x4 = reinterpret_cast<const float4*>(x);
    float4* __restrict__ o4 = reinterpret_cast<float4*>(out);

    float u = 0.0f;
    bool sprev = false;

    for (int k = 0; k < NCH; ++k) {
        const int t0q = k * (CT / 4);  // float4 offset of this chunk within a row

        // ---- stage: coalesced global float4 loads -> LDS (b128 writes, conflict-free) ----
        #pragma unroll
        for (int i = 0; i < 8; ++i) {
            int flat = i * RPB + tid;        // float4 index within the chunk tile
            int row  = flat >> 3;            // local row 0..255
            int g    = flat & 7;             // float4 slot within the 32-t chunk
            float4 v = x4[(rbase + row) * (T_LEN / 4) + t0q + g];
            *reinterpret_cast<float4*>(&xs[row * XS_STRIDE + 4 * g]) = v;
        }
        __syncthreads();

        // ---- compute: own row, 32 sequential steps from registers ----
        float4 v[8];
        #pragma unroll
        for (int i = 0; i < 8; ++i)
            v[i] = *reinterpret_cast<const float4*>(&xs[tid * XS_STRIDE + 4 * i]);

        unsigned int m = 0;
        #pragma unroll
        for (int i = 0; i < 8; ++i) {
            float e0 = v[i].x, e1 = v[i].y, e2 = v[i].z, e3 = v[i].w;
            // Bit-exact vs reference:  u = (TAU*u)*(1-s) + x  ==  select + mul + add (no FMA)
            {
                float um = sprev ? 0.0f : __fmul_rn(TAU, u);
                u = __fadd_rn(um, e0);
                sprev = u > VTH;
                m |= (sprev ? 1u : 0u) << (i * 4 + 0);
            }
            {
                float um = sprev ? 0.0f : __fmul_rn(TAU, u);
                u = __fadd_rn(um, e1);
                sprev = u > VTH;
                m |= (sprev ? 1u : 0u) << (i * 4 + 1);
            }
            {
                float um = sprev ? 0.0f : __fmul_rn(TAU, u);
                u = __fadd_rn(um, e2);
                sprev = u > VTH;
                m |= (sprev ? 1u : 0u) << (i * 4 + 2);
            }
            {
                float um = sprev ? 0.0f : __fmul_rn(TAU, u);
                u = __fadd_rn(um, e3);
                sprev = u > VTH;
                m |= (sprev ? 1u : 0u) << (i * 4 + 3);
            }
        }
        smask[tid] = m;
        __syncthreads();

        // ---- output: expand masks -> coalesced float4 stores ----
        #pragma unroll
        for (int i = 0; i < 8; ++i) {
            int flat = i * RPB + tid;
            int row  = flat >> 3;
            int g    = flat & 7;
            unsigned int mr = smask[row];    // 8 lanes share an address -> LDS broadcast
            int toff = 4 * g;
            float4 o;
            o.x = ((mr >> (toff + 0)) & 1u) ? 1.0f : 0.0f;
            o.y = ((mr >> (toff + 1)) & 1u) ? 1.0f : 0.0f;
            o.z = ((mr >> (toff + 2)) & 1u) ? 1.0f : 0.0f;
            o.w = ((mr >> (toff + 3)) & 1u) ? 1.0f : 0.0f;
            o4[(rbase + row) * (T_LEN / 4) + t0q + g] = o;
        }
        // No third barrier needed: next stage writes xs (all xs reads completed
        // before the second barrier); next compute writes smask only after the
        // next first barrier, by which time all smask reads above are done.
    }
}

extern "C" void kernel_launch(void* const* d_in, const int* in_sizes, int n_in,
                              void* d_out, int out_size, void* d_ws, size_t ws_size,
                              hipStream_t stream) {
    const float* x = (const float*)d_in[0];
    float* out = (float*)d_out;
    const int total = in_sizes[0];          // 64*2048*256
    const int nrows = total / T_LEN;        // 131072
    const int blocks = nrows / RPB;         // 512
    lif_kernel<<<blocks, RPB, 0, stream>>>(x, out);
}

// Round 2
// 44.769 us; speedup vs baseline: 1.0386x; 1.0386x over previous
//
#include <hip/hip_runtime.h>

// LIF integrate-fire-reset over the time axis.
// x: [B=64, C=2048, T=256] f32 row-major -> 131072 rows of 256 contiguous floats.
// u_t = TAU*u_{t-1}*(1-s_{t-1}) + x_t ; s_t = (u_t > VTH).
//
// One thread per row. Per 32-step chunk:
//   - coalesced float4 global loads staged to LDS (stride-36 rows: conflict-free
//     for both b128 writes and b128 reads) with DOUBLE BUFFERING,
//   - next chunk prefetched into registers right after the barrier (HBM latency
//     hides under the serial 32-step integrate chain),
//   - lgkmcnt-only barrier (raw s_barrier; never drains vmcnt, so prefetch loads
//     and output stores stay in flight across chunks),
//   - spikes packed to a 32-bit mask, exchanged wave-locally via __shfl (no LDS,
//     no second barrier), expanded and stored as NONTEMPORAL float4 (keeps the
//     128 MiB input resident in L3 instead of letting output writes evict it).

#define T_LEN 256
#define TQ 64              // float4 per row
#define NCH 8              // 8 chunks of 32 timesteps
#define RPB 256            // rows per block == threads per block
#define XS_STRIDE 36       // LDS words per row (32 + 4 pad)

#define TAU 0.25f
#define VTH 0.5f

typedef float f32x4 __attribute__((ext_vector_type(4)));

__global__ __launch_bounds__(RPB, 2)
void lif_kernel(const float* __restrict__ x, float* __restrict__ out) {
    __shared__ __align__(16) float xs[2][RPB * XS_STRIDE];  // 2 x 36864 B

    const int tid  = threadIdx.x;
    const int lane = tid & 63;
    const int wv   = tid >> 6;
    const long rbase = (long)blockIdx.x * RPB;

    const float4* __restrict__ x4 = reinterpret_cast<const float4*>(x);
    float* __restrict__ outp = out;

    const int qs = tid & 7;   // float4 slot this thread stages
    const int rs = tid >> 3;  // base staging row (stride 32 per i)

    // ---- prologue: prefetch chunk 0 into registers ----
    float4 p[8];
    #pragma unroll
    for (int i = 0; i < 8; ++i)
        p[i] = x4[(rbase + rs + i * 32) * TQ + qs];

    float u = 0.0f;
    bool sprev = false;

    #pragma unroll
    for (int k = 0; k < NCH; ++k) {
        float* buf = xs[k & 1];

        // ---- stage chunk k: regs -> LDS (b128, conflict-free) ----
        #pragma unroll
        for (int i = 0; i < 8; ++i)
            *reinterpret_cast<float4*>(&buf[(rs + i * 32) * XS_STRIDE + 4 * qs]) = p[i];

        // lgkm-only barrier: do NOT drain vmcnt (stores/prefetch stay in flight)
        asm volatile("s_waitcnt lgkmcnt(0)" ::: "memory");
        __builtin_amdgcn_s_barrier();

        // ---- prefetch chunk k+1 (in flight during the serial compute) ----
        if (k + 1 < NCH) {
            #pragma unroll
            for (int i = 0; i < 8; ++i)
                p[i] = x4[(rbase + rs + i * 32) * TQ + (k + 1) * 8 + qs];
        }

        // ---- read own row from LDS ----
        float4 v[8];
        #pragma unroll
        for (int i = 0; i < 8; ++i)
            v[i] = *reinterpret_cast<const float4*>(&buf[tid * XS_STRIDE + 4 * i]);

        // ---- 32 sequential LIF steps, bit-exact vs reference ----
        unsigned int m = 0;
        #pragma unroll
        for (int i = 0; i < 8; ++i) {
            float e[4] = { v[i].x, v[i].y, v[i].z, v[i].w };
            #pragma unroll
            for (int j = 0; j < 4; ++j) {
                float um = sprev ? 0.0f : __fmul_rn(TAU, u);
                u = __fadd_rn(um, e[j]);
                sprev = u > VTH;
                m |= (sprev ? 1u : 0u) << (i * 4 + j);
            }
        }

        // ---- wave-local mask exchange + nontemporal coalesced stores ----
        #pragma unroll
        for (int i = 0; i < 8; ++i) {
            int rowl = i * 8 + (lane >> 3);                       // row within wave tile
            unsigned int mr = (unsigned int)__shfl((int)m, rowl, 64);
            int toff = 4 * (lane & 7);
            f32x4 o;
            o[0] = ((mr >> (toff + 0)) & 1u) ? 1.0f : 0.0f;
            o[1] = ((mr >> (toff + 1)) & 1u) ? 1.0f : 0.0f;
            o[2] = ((mr >> (toff + 2)) & 1u) ? 1.0f : 0.0f;
            o[3] = ((mr >> (toff + 3)) & 1u) ? 1.0f : 0.0f;
            long gq = (rbase + wv * 64 + rowl) * (long)TQ + k * 8 + (lane & 7);
            __builtin_nontemporal_store(o, reinterpret_cast<f32x4*>(outp) + gq);
        }
        // Next iteration writes the OTHER LDS buffer; its prior readers finished
        // before the barrier above (lgkmcnt(0) precedes s_barrier). One barrier
        // per chunk is sufficient.
    }
}

extern "C" void kernel_launch(void* const* d_in, const int* in_sizes, int n_in,
                              void* d_out, int out_size, void* d_ws, size_t ws_size,
                              hipStream_t stream) {
    const float* x = (const float*)d_in[0];
    float* out = (float*)d_out;
    const int total = in_sizes[0];      // 64*2048*256
    const int nrows = total / T_LEN;    // 131072
    const int blocks = nrows / RPB;     // 512
    lif_kernel<<<blocks, RPB, 0, stream>>>(x, out);
}